// Round 16
// baseline (223.375 us; speedup 1.0000x reference)
//
#include <hip/hip_runtime.h>

#define DD 128   // feature dim
#define KY 512   // y columns (R * DD)
#define KT 640   // total GEMM K (KY + DD)
#define RR 4     // relations
#define BKT 16   // ints per (relation,node) bucket: [count, slot0..slot14]
#define CAPS 15  // usable slots per bucket
#define NKS (KT / 32)   // 20 K-steps

typedef short short8 __attribute__((ext_vector_type(8)));
typedef float f32x4 __attribute__((ext_vector_type(4)));

union U4S8 { uint4 u; short8 s; };

__device__ __forceinline__ unsigned short f2bf(float f) {
  unsigned u = __float_as_uint(f);
  u += 0x7fffu + ((u >> 16) & 1u);   // round-to-nearest-even
  return (unsigned short)(u >> 16);
}

// ---- 1. fused prep: fill_slots FIRST, 4 edges/thread (MLP-4 = measured
//         optimum: MLP1 54.5 / MLP2 53 / MLP4 49.2 / MLP8 54); then xcast
//         (streams under the scatter), then wcast. r12/r14 verbatim. ----
// bucket layout node-major: slot[n*64 + r*16 + 0] = count, [+1..+15] = src ids.
// Count+slots share one 64B line -> ONE random line touch per edge (r4-verified).
__global__ __launch_bounds__(256) void prep(const float* __restrict__ x,
                                            const float* __restrict__ weight,
                                            const float* __restrict__ loopw,
                                            const int* __restrict__ src,
                                            const int* __restrict__ dst,
                                            unsigned short* __restrict__ xb,
                                            unsigned short* __restrict__ wt,
                                            int* __restrict__ slot,
                                            int N, int E, int FB, int XB) {
  int b = blockIdx.x;
  int t = threadIdx.x;
  if (b < FB) {
    // fill_slots: 4 edges per thread, int4-coalesced; independent atomics
    int i = (b * 256 + t) * 4;                  // RR*E divisible by 4
    if (i >= RR * E) return;
    int4 dp = *(const int4*)(dst + i);
    int4 sp = *(const int4*)(src + i);
    int r0 = i / E, r1 = (i + 1) / E, r2 = (i + 2) / E, r3 = (i + 3) / E;
    size_t b0 = ((size_t)dp.x * RR + r0) * BKT;
    size_t b1 = ((size_t)dp.y * RR + r1) * BKT;
    size_t b2 = ((size_t)dp.z * RR + r2) * BKT;
    size_t b3 = ((size_t)dp.w * RR + r3) * BKT;
    int p0 = atomicAdd(slot + b0, 1);
    int p1 = atomicAdd(slot + b1, 1);
    int p2 = atomicAdd(slot + b2, 1);
    int p3 = atomicAdd(slot + b3, 1);
    if (p0 < CAPS) slot[b0 + 1 + p0] = sp.x;
    if (p1 < CAPS) slot[b1 + 1 + p1] = sp.y;
    if (p2 < CAPS) slot[b2 + 1 + p2] = sp.z;
    if (p3 < CAPS) slot[b3 + 1 + p3] = sp.w;
  } else if (b < FB + XB) {
    // xcast: 8 floats per thread over N+1 rows (row N = zeros)
    int i = (b - FB) * 256 + t;
    if (i >= (N + 1) * 16) return;
    int n = i >> 4;
    uint4 o = make_uint4(0, 0, 0, 0);
    if (n < N) {
      const float4* xp = (const float4*)x + (size_t)i * 2;
      float4 v0 = xp[0], v1 = xp[1];
      o.x = (unsigned)f2bf(v0.x) | ((unsigned)f2bf(v0.y) << 16);
      o.y = (unsigned)f2bf(v0.z) | ((unsigned)f2bf(v0.w) << 16);
      o.z = (unsigned)f2bf(v1.x) | ((unsigned)f2bf(v1.y) << 16);
      o.w = (unsigned)f2bf(v1.z) | ((unsigned)f2bf(v1.w) << 16);
    }
    ((uint4*)xb)[i] = o;
  } else {
    // wcast into kstep-tile layout:
    // i = ks*4096 + c*512 + l*8 + j -> B[k = ks*32+(l>>4)*8+j][col = c*16+(l&15)]
    int i = (b - FB - XB) * 256 + t;
    if (i >= DD * KT) return;
    int j = i & 7, l = (i >> 3) & 63, c = (i >> 9) & 7, ks = i >> 12;
    int k = ks * 32 + (l >> 4) * 8 + j;
    int col = c * 16 + (l & 15);
    float v = (k < KY) ? weight[(size_t)((k >> 7) * DD + (k & (DD - 1))) * DD + col]
                       : loopw[(size_t)(k - KY) * DD + col];
    wt[i] = f2bf(v);
  }
}

// ---- 2. gather-aggregate: TWO waves per node (NEW). Wave handles relation
//         pair p = (wid&1)*2: loads its 128B half-bucket (lane&31), runs ONE
//         relation-pair loop (~2.3 dependent rounds vs ~4.6), writes its two
//         y-slices. Wave count doubles (50k) -> per-wave serial path halves
//         at the same total traffic (slot bytes unchanged: half-bucket each).
__global__ __launch_bounds__(256) void gather_agg(const unsigned* __restrict__ xbu,
                                                  const int* __restrict__ slot,
                                                  unsigned* __restrict__ yu,
                                                  int NN /* = N+1 */) {
  int gid = blockIdx.x * 256 + threadIdx.x;
  int wid = gid >> 6, lane = gid & 63;
  int n = wid >> 1, p = (wid & 1) * 2;          // relation pair p, p+1
  if (n >= NN) return;
  int N = NN - 1;  // zero-row index

  // this wave's 2 buckets (128B) in one coalesced load (lanes 0-31 distinct)
  int sv = slot[(size_t)n * 64 + (p << 4) + (lane & 31)];

  int ct0 = __builtin_amdgcn_readlane(sv, 0);   // count of rel p   (lane 0)
  int ct1 = __builtin_amdgcn_readlane(sv, 16);  // count of rel p+1 (lane 16)
  int cn0 = ct0 > CAPS ? CAPS : ct0;
  int cn1 = ct1 > CAPS ? CAPS : ct1;

  float ax0 = 0.f, ay0 = 0.f, ax1 = 0.f, ay1 = 0.f;

  int mx = max(cn0, cn1);
  for (int u = 0; u < mx; u += 2) {             // uniform trip count (SGPR)
    int s0 = __builtin_amdgcn_readlane(sv, (1 + u) & 63);
    int s1 = __builtin_amdgcn_readlane(sv, (2 + u) & 63);
    int s2 = __builtin_amdgcn_readlane(sv, (17 + u) & 63);
    int s3 = __builtin_amdgcn_readlane(sv, (18 + u) & 63);
    s0 = (u < cn0) ? s0 : N;                    // pad -> zero row
    s1 = (u + 1 < cn0) ? s1 : N;
    s2 = (u < cn1) ? s2 : N;
    s3 = (u + 1 < cn1) ? s3 : N;
    unsigned v0 = xbu[(size_t)s0 * 64 + lane];
    unsigned v1 = xbu[(size_t)s1 * 64 + lane];
    unsigned v2 = xbu[(size_t)s2 * 64 + lane];
    unsigned v3 = xbu[(size_t)s3 * 64 + lane];
    ax0 += __uint_as_float(v0 << 16);
    ay0 += __uint_as_float(v0 & 0xffff0000u);
    ax0 += __uint_as_float(v1 << 16);
    ay0 += __uint_as_float(v1 & 0xffff0000u);
    ax1 += __uint_as_float(v2 << 16);
    ay1 += __uint_as_float(v2 & 0xffff0000u);
    ax1 += __uint_as_float(v3 << 16);
    ay1 += __uint_as_float(v3 & 0xffff0000u);
  }

  float inv0 = 1.0f / (float)max(ct0, 1);
  float inv1 = 1.0f / (float)max(ct1, 1);
  yu[(size_t)n * (KY / 2) + p * 64 + lane] =
      (unsigned)f2bf(ax0 * inv0) | ((unsigned)f2bf(ay0 * inv0) << 16);
  yu[(size_t)n * (KY / 2) + (p + 1) * 64 + lane] =
      (unsigned)f2bf(ax1 * inv1) | ((unsigned)f2bf(ay1 * inv1) << 16);
}

// ---- 3. MFMA GEMM: out = relu([y|xb][N,640] @ Wcat + bias) ----
// r11/r14-verified local optimum: 128 rows / 256 threads, 782 blocks (~3/CU),
// 32-row waves, per-kstep 2-barrier loop. Probed and rejected: A-prefetch
// (r12 +5us), BK=64 (r15 +4us), 16-row waves (r6 +13us), 512-thr (r7 +4us).
// A: direct global->VGPR, coalesced. B: double-buffered LDS, lane-linear
// kstep tiles (conflict-free ds_read_b128), 1-step reg prefetch.
__global__ __launch_bounds__(256) void gemm_mfma(const unsigned short* __restrict__ y,
                                                 const unsigned short* __restrict__ xb,
                                                 const uint4* __restrict__ wtv,
                                                 const float* __restrict__ bias,
                                                 float* __restrict__ out, int N) {
  __shared__ __align__(16) unsigned short Bs[2][4096];   // 16 KB total
  int t = threadIdx.x;
  int w = t >> 6, lane = t & 63;
  int m = lane & 15, q = lane >> 4;
  int rb = blockIdx.x * 128;

  int grow0 = rb + w * 32 + m, grow1 = grow0 + 16;
  int r0c = grow0 > N ? N : grow0;   // clamp to zero row N
  int r1c = grow1 > N ? N : grow1;
  const unsigned short* ay0 = y  + (size_t)r0c * KY + q * 8;
  const unsigned short* ay1 = y  + (size_t)r1c * KY + q * 8;
  const unsigned short* ax0 = xb + (size_t)r0c * DD + q * 8;
  const unsigned short* ax1 = xb + (size_t)r1c * DD + q * 8;

  // stage B kstep 0 (contiguous copy: 256 threads x 2 uint4)
  *(uint4*)(&Bs[0][t * 8]) = wtv[t];
  *(uint4*)(&Bs[0][2048 + t * 8]) = wtv[256 + t];
  __syncthreads();

  f32x4 acc[2][8];
#pragma unroll
  for (int i = 0; i < 2; i++)
#pragma unroll
    for (int c = 0; c < 8; c++) acc[i][c] = (f32x4){0.f, 0.f, 0.f, 0.f};

#pragma unroll
  for (int ks = 0; ks < NKS; ++ks) {
    const int buf = ks & 1;
    // issue-early: next B tile global->reg
    uint4 bs0, bs1;
    if (ks + 1 < NKS) {
      bs0 = wtv[(size_t)(ks + 1) * 512 + t];
      bs1 = wtv[(size_t)(ks + 1) * 512 + 256 + t];
    }

    // A fragments straight from global (compile-time y/xb branch)
    U4S8 a0, a1;
    if (ks < 16) {
      a0.u = *(const uint4*)(ay0 + ks * 32);
      a1.u = *(const uint4*)(ay1 + ks * 32);
    } else {
      a0.u = *(const uint4*)(ax0 + (ks - 16) * 32);
      a1.u = *(const uint4*)(ax1 + (ks - 16) * 32);
    }

    // B fragments: lane-linear -> conflict-free
    short8 bb[8];
#pragma unroll
    for (int c = 0; c < 8; ++c)
      bb[c] = *(const short8*)(&Bs[buf][(c * 64 + lane) * 8]);

#pragma unroll
    for (int c = 0; c < 8; ++c) {
      acc[0][c] = __builtin_amdgcn_mfma_f32_16x16x32_bf16(a0.s, bb[c], acc[0][c], 0, 0, 0);
      acc[1][c] = __builtin_amdgcn_mfma_f32_16x16x32_bf16(a1.s, bb[c], acc[1][c], 0, 0, 0);
    }

    // write-late: commit next B tile, then barrier
    if (ks + 1 < NKS) {
      *(uint4*)(&Bs[buf ^ 1][t * 8]) = bs0;
      *(uint4*)(&Bs[buf ^ 1][2048 + t * 8]) = bs1;
      __syncthreads();
    }
  }

  float bv[8];
#pragma unroll
  for (int c = 0; c < 8; ++c) bv[c] = bias[c * 16 + m];
#pragma unroll
  for (int i = 0; i < 2; ++i) {
    int rbase = rb + w * 32 + i * 16 + q * 4;
#pragma unroll
    for (int v = 0; v < 4; ++v) {
      int gr = rbase + v;
      if (gr < N) {
#pragma unroll
        for (int c = 0; c < 8; ++c)
          out[(size_t)gr * DD + c * 16 + m] = fmaxf(acc[i][c][v] + bv[c], 0.f);
      }
    }
  }
}

extern "C" void kernel_launch(void* const* d_in, const int* in_sizes, int n_in,
                              void* d_out, int out_size, void* d_ws, size_t ws_size,
                              hipStream_t stream) {
  const float* x      = (const float*)d_in[0];  // [N,128]
  const float* weight = (const float*)d_in[1];  // [R,128,128]
  const float* loop_w = (const float*)d_in[2];  // [128,128]
  const float* h_bias = (const float*)d_in[3];  // [128]
  const int*   src    = (const int*)d_in[4];    // [R,E]
  const int*   dst    = (const int*)d_in[5];    // [R,E]
  float* out = (float*)d_out;                   // [N,128]

  const int N = in_sizes[0] / DD;
  const int R = in_sizes[1] / (DD * DD);        // == RR == 4
  const int E = in_sizes[4] / R;
  const int RE = R * E;

  char* p = (char*)d_ws;
  auto alloc = [&](size_t bytes) {
    char* q = p;
    p += (bytes + 63) & ~size_t(63);
    return q;
  };
  int* slot = (int*)alloc((size_t)(N + 1) * RR * BKT * 4);      // [N+1][4][16] node-major
  unsigned short* wt = (unsigned short*)alloc((size_t)DD * KT * 2);
  unsigned short* xb = (unsigned short*)alloc((size_t)(N + 1) * DD * 2);  // +zero row
  unsigned short* y  = (unsigned short*)alloc((size_t)(N + 1) * KY * 2);  // +zero row

  hipMemsetAsync(slot, 0, (size_t)(N + 1) * RR * BKT * 4, stream);

  int FB = (RE / 4 + 255) / 256;                // 4 edges/thread (MLP-4 optimum)
  int XB = ((N + 1) * 16 + 255) / 256;
  int WB = (DD * KT + 255) / 256;
  prep<<<FB + XB + WB, 256, 0, stream>>>(x, weight, loop_w, src, dst,
                                         xb, wt, slot, N, E, FB, XB);
  gather_agg<<<((size_t)(N + 1) * 128 + 255) / 256, 256, 0, stream>>>(
      (const unsigned*)xb, slot, (unsigned*)y, N + 1);
  gemm_mfma<<<(N + 127) / 128, 256, 0, stream>>>(y, xb, (const uint4*)wt,
                                                 h_bias, out, N);
}

// Round 17
// 217.494 us; speedup vs baseline: 1.0270x; 1.0270x over previous
//
#include <hip/hip_runtime.h>

#define DD 128   // feature dim
#define KY 512   // y columns (R * DD)
#define KT 640   // total GEMM K (KY + DD)
#define RR 4     // relations
#define BKT 16   // ints per (relation,node) bucket: [count, slot0..slot14]
#define CAPS 15  // usable slots per bucket
#define NKS (KT / 32)   // 20 K-steps

typedef short short8 __attribute__((ext_vector_type(8)));
typedef float f32x4 __attribute__((ext_vector_type(4)));

union U4S8 { uint4 u; short8 s; };

__device__ __forceinline__ unsigned short f2bf(float f) {
  unsigned u = __float_as_uint(f);
  u += 0x7fffu + ((u >> 16) & 1u);   // round-to-nearest-even
  return (unsigned short)(u >> 16);
}

// ---- 1. fused prep: fill_slots FIRST, 4 edges/thread (MLP-4 = measured
//         optimum: MLP1 54.5 / MLP2 53 / MLP4 49.2 / MLP8 54); then xcast
//         (streams under the scatter), then wcast. r12/r14 verbatim. ----
// bucket layout node-major: slot[n*64 + r*16 + 0] = count, [+1..+15] = src ids.
// Count+slots share one 64B line -> ONE random line touch per edge (r4-verified).
__global__ __launch_bounds__(256) void prep(const float* __restrict__ x,
                                            const float* __restrict__ weight,
                                            const float* __restrict__ loopw,
                                            const int* __restrict__ src,
                                            const int* __restrict__ dst,
                                            unsigned short* __restrict__ xb,
                                            unsigned short* __restrict__ wt,
                                            int* __restrict__ slot,
                                            int N, int E, int FB, int XB) {
  int b = blockIdx.x;
  int t = threadIdx.x;
  if (b < FB) {
    // fill_slots: 4 edges per thread, int4-coalesced; independent atomics
    int i = (b * 256 + t) * 4;                  // RR*E divisible by 4
    if (i >= RR * E) return;
    int4 dp = *(const int4*)(dst + i);
    int4 sp = *(const int4*)(src + i);
    int r0 = i / E, r1 = (i + 1) / E, r2 = (i + 2) / E, r3 = (i + 3) / E;
    size_t b0 = ((size_t)dp.x * RR + r0) * BKT;
    size_t b1 = ((size_t)dp.y * RR + r1) * BKT;
    size_t b2 = ((size_t)dp.z * RR + r2) * BKT;
    size_t b3 = ((size_t)dp.w * RR + r3) * BKT;
    int p0 = atomicAdd(slot + b0, 1);
    int p1 = atomicAdd(slot + b1, 1);
    int p2 = atomicAdd(slot + b2, 1);
    int p3 = atomicAdd(slot + b3, 1);
    if (p0 < CAPS) slot[b0 + 1 + p0] = sp.x;
    if (p1 < CAPS) slot[b1 + 1 + p1] = sp.y;
    if (p2 < CAPS) slot[b2 + 1 + p2] = sp.z;
    if (p3 < CAPS) slot[b3 + 1 + p3] = sp.w;
  } else if (b < FB + XB) {
    // xcast: 8 floats per thread over N+1 rows (row N = zeros)
    int i = (b - FB) * 256 + t;
    if (i >= (N + 1) * 16) return;
    int n = i >> 4;
    uint4 o = make_uint4(0, 0, 0, 0);
    if (n < N) {
      const float4* xp = (const float4*)x + (size_t)i * 2;
      float4 v0 = xp[0], v1 = xp[1];
      o.x = (unsigned)f2bf(v0.x) | ((unsigned)f2bf(v0.y) << 16);
      o.y = (unsigned)f2bf(v0.z) | ((unsigned)f2bf(v0.w) << 16);
      o.z = (unsigned)f2bf(v1.x) | ((unsigned)f2bf(v1.y) << 16);
      o.w = (unsigned)f2bf(v1.z) | ((unsigned)f2bf(v1.w) << 16);
    }
    ((uint4*)xb)[i] = o;
  } else {
    // wcast into kstep-tile layout:
    // i = ks*4096 + c*512 + l*8 + j -> B[k = ks*32+(l>>4)*8+j][col = c*16+(l&15)]
    int i = (b - FB - XB) * 256 + t;
    if (i >= DD * KT) return;
    int j = i & 7, l = (i >> 3) & 63, c = (i >> 9) & 7, ks = i >> 12;
    int k = ks * 32 + (l >> 4) * 8 + j;
    int col = c * 16 + (l & 15);
    float v = (k < KY) ? weight[(size_t)((k >> 7) * DD + (k & (DD - 1))) * DD + col]
                       : loopw[(size_t)(k - KY) * DD + col];
    wt[i] = f2bf(v);
  }
}

// ---- 2. gather-aggregate (r11 loop body — the measured best): one wave per
//         node, relation-pair loops, 4 independent loads/iter, wave-uniform
//         trip counts. NEW: y written KSTEP-MAJOR — yu[(kk*NN + n)*16 + cu]
//         with kk = r*4 + (lane>>4), cu = lane&15 — so the GEMM's A-loads
//         become fully-contiguous 2KB/wave. 16-lane groups still write 64B
//         contiguous runs (write coalescing unchanged).
__global__ __launch_bounds__(256) void gather_agg(const unsigned* __restrict__ xbu,
                                                  const int* __restrict__ slot,
                                                  unsigned* __restrict__ yu,
                                                  int NN /* = N+1 */) {
  int gid = blockIdx.x * 256 + threadIdx.x;
  int n = gid >> 6, lane = gid & 63;
  if (n >= NN) return;
  int N = NN - 1;  // zero-row index

  // all 4 buckets of this node in one coalesced 256B load (lane = r*16+j)
  int sv = slot[(size_t)n * 64 + lane];

  int cn[RR], ct[RR];
#pragma unroll
  for (int r = 0; r < RR; r++) {
    ct[r] = __builtin_amdgcn_readlane(sv, r << 4);    // count word (SGPR)
    cn[r] = ct[r] > CAPS ? CAPS : ct[r];
  }

  float ax[RR], ay[RR];
#pragma unroll
  for (int r = 0; r < RR; r++) { ax[r] = 0.f; ay[r] = 0.f; }

#pragma unroll
  for (int rp = 0; rp < RR; rp += 2) {
    int mx = max(cn[rp], cn[rp + 1]);
    for (int u = 0; u < mx; u += 2) {                 // uniform trip count
      int i0 = (rp << 4) + 1 + u;
      int s0 = __builtin_amdgcn_readlane(sv, i0 & 63);
      int s1 = __builtin_amdgcn_readlane(sv, (i0 + 1) & 63);
      int s2 = __builtin_amdgcn_readlane(sv, (i0 + 16) & 63);
      int s3 = __builtin_amdgcn_readlane(sv, (i0 + 17) & 63);
      s0 = (u < cn[rp]) ? s0 : N;                     // pad -> zero row
      s1 = (u + 1 < cn[rp]) ? s1 : N;
      s2 = (u < cn[rp + 1]) ? s2 : N;
      s3 = (u + 1 < cn[rp + 1]) ? s3 : N;
      unsigned v0 = xbu[(size_t)s0 * 64 + lane];
      unsigned v1 = xbu[(size_t)s1 * 64 + lane];
      unsigned v2 = xbu[(size_t)s2 * 64 + lane];
      unsigned v3 = xbu[(size_t)s3 * 64 + lane];
      ax[rp] += __uint_as_float(v0 << 16);
      ay[rp] += __uint_as_float(v0 & 0xffff0000u);
      ax[rp] += __uint_as_float(v1 << 16);
      ay[rp] += __uint_as_float(v1 & 0xffff0000u);
      ax[rp + 1] += __uint_as_float(v2 << 16);
      ay[rp + 1] += __uint_as_float(v2 & 0xffff0000u);
      ax[rp + 1] += __uint_as_float(v3 << 16);
      ay[rp + 1] += __uint_as_float(v3 & 0xffff0000u);
    }
  }

  // kstep-major y write: kk = r*4 + (lane>>4), cu = lane&15
  int kk_lo = lane >> 4, cu = lane & 15;
#pragma unroll
  for (int r = 0; r < RR; r++) {
    float inv = 1.0f / (float)max(ct[r], 1);
    yu[((size_t)(r * 4 + kk_lo) * NN + n) * 16 + cu] =
        (unsigned)f2bf(ax[r] * inv) | ((unsigned)f2bf(ay[r] * inv) << 16);
  }
}

// ---- 3. MFMA GEMM: out = relu([y|xb][N,640] @ Wcat + bias) ----
// r11/r14 structure (probed+rejected: A-prefetch r12, BK=64 r15, 16-row waves
// r6, 512-thr r7). NEW: y is kstep-major, so the per-kstep A-load is one
// fully-contiguous 2KB block per wave (32 consecutive nodes x 64B) -> every
// fetched 128B line 100% consumed. A: direct global->VGPR. B: double-buffered
// LDS, lane-linear kstep tiles (conflict-free ds_read_b128), 1-step prefetch.
__global__ __launch_bounds__(256) void gemm_mfma(const unsigned* __restrict__ yu,
                                                 const unsigned short* __restrict__ xb,
                                                 const uint4* __restrict__ wtv,
                                                 const float* __restrict__ bias,
                                                 float* __restrict__ out, int N, int NN) {
  __shared__ __align__(16) unsigned short Bs[2][4096];   // 16 KB total
  int t = threadIdx.x;
  int w = t >> 6, lane = t & 63;
  int m = lane & 15, q = lane >> 4;
  int rb = blockIdx.x * 128;

  int grow0 = rb + w * 32 + m, grow1 = grow0 + 16;
  int r0c = grow0 > N ? N : grow0;   // clamp to zero row N
  int r1c = grow1 > N ? N : grow1;
  const unsigned short* ax0 = xb + (size_t)r0c * DD + q * 8;
  const unsigned short* ax1 = xb + (size_t)r1c * DD + q * 8;

  // stage B kstep 0 (contiguous copy: 256 threads x 2 uint4)
  *(uint4*)(&Bs[0][t * 8]) = wtv[t];
  *(uint4*)(&Bs[0][2048 + t * 8]) = wtv[256 + t];
  __syncthreads();

  f32x4 acc[2][8];
#pragma unroll
  for (int i = 0; i < 2; i++)
#pragma unroll
    for (int c = 0; c < 8; c++) acc[i][c] = (f32x4){0.f, 0.f, 0.f, 0.f};

#pragma unroll
  for (int ks = 0; ks < NKS; ++ks) {
    const int buf = ks & 1;
    // issue-early: next B tile global->reg
    uint4 bs0, bs1;
    if (ks + 1 < NKS) {
      bs0 = wtv[(size_t)(ks + 1) * 512 + t];
      bs1 = wtv[(size_t)(ks + 1) * 512 + 256 + t];
    }

    // A fragments straight from global (compile-time y/xb branch)
    U4S8 a0, a1;
    if (ks < 16) {
      // kstep-major y: wave covers 32 consecutive nodes -> 2KB contiguous
      const unsigned* yb = yu + (size_t)ks * NN * 16 + q * 4;
      a0.u = *(const uint4*)(yb + (size_t)r0c * 16);
      a1.u = *(const uint4*)(yb + (size_t)r1c * 16);
    } else {
      a0.u = *(const uint4*)(ax0 + (ks - 16) * 32);
      a1.u = *(const uint4*)(ax1 + (ks - 16) * 32);
    }

    // B fragments: lane-linear -> conflict-free
    short8 bb[8];
#pragma unroll
    for (int c = 0; c < 8; ++c)
      bb[c] = *(const short8*)(&Bs[buf][(c * 64 + lane) * 8]);

#pragma unroll
    for (int c = 0; c < 8; ++c) {
      acc[0][c] = __builtin_amdgcn_mfma_f32_16x16x32_bf16(a0.s, bb[c], acc[0][c], 0, 0, 0);
      acc[1][c] = __builtin_amdgcn_mfma_f32_16x16x32_bf16(a1.s, bb[c], acc[1][c], 0, 0, 0);
    }

    // write-late: commit next B tile, then barrier
    if (ks + 1 < NKS) {
      *(uint4*)(&Bs[buf ^ 1][t * 8]) = bs0;
      *(uint4*)(&Bs[buf ^ 1][2048 + t * 8]) = bs1;
      __syncthreads();
    }
  }

  float bv[8];
#pragma unroll
  for (int c = 0; c < 8; ++c) bv[c] = bias[c * 16 + m];
#pragma unroll
  for (int i = 0; i < 2; ++i) {
    int rbase = rb + w * 32 + i * 16 + q * 4;
#pragma unroll
    for (int v = 0; v < 4; ++v) {
      int gr = rbase + v;
      if (gr < N) {
#pragma unroll
        for (int c = 0; c < 8; ++c)
          out[(size_t)gr * DD + c * 16 + m] = fmaxf(acc[i][c][v] + bv[c], 0.f);
      }
    }
  }
}

extern "C" void kernel_launch(void* const* d_in, const int* in_sizes, int n_in,
                              void* d_out, int out_size, void* d_ws, size_t ws_size,
                              hipStream_t stream) {
  const float* x      = (const float*)d_in[0];  // [N,128]
  const float* weight = (const float*)d_in[1];  // [R,128,128]
  const float* loop_w = (const float*)d_in[2];  // [128,128]
  const float* h_bias = (const float*)d_in[3];  // [128]
  const int*   src    = (const int*)d_in[4];    // [R,E]
  const int*   dst    = (const int*)d_in[5];    // [R,E]
  float* out = (float*)d_out;                   // [N,128]

  const int N = in_sizes[0] / DD;
  const int R = in_sizes[1] / (DD * DD);        // == RR == 4
  const int E = in_sizes[4] / R;
  const int RE = R * E;
  const int NN = N + 1;

  char* p = (char*)d_ws;
  auto alloc = [&](size_t bytes) {
    char* q = p;
    p += (bytes + 63) & ~size_t(63);
    return q;
  };
  int* slot = (int*)alloc((size_t)NN * RR * BKT * 4);           // [N+1][4][16] node-major
  unsigned short* wt = (unsigned short*)alloc((size_t)DD * KT * 2);
  unsigned short* xb = (unsigned short*)alloc((size_t)NN * DD * 2);  // +zero row
  unsigned short* y  = (unsigned short*)alloc((size_t)NN * KY * 2);  // kstep-major [16][NN][32]

  hipMemsetAsync(slot, 0, (size_t)NN * RR * BKT * 4, stream);

  int FB = (RE / 4 + 255) / 256;                // 4 edges/thread (MLP-4 optimum)
  int XB = (NN * 16 + 255) / 256;
  int WB = (DD * KT + 255) / 256;
  prep<<<FB + XB + WB, 256, 0, stream>>>(x, weight, loop_w, src, dst,
                                         xb, wt, slot, N, E, FB, XB);
  gather_agg<<<((size_t)NN * 64 + 255) / 256, 256, 0, stream>>>(
      (const unsigned*)xb, slot, (unsigned*)y, NN);
  gemm_mfma<<<(N + 127) / 128, 256, 0, stream>>>((const unsigned*)y, xb,
                                                 (const uint4*)wt, h_bias, out,
                                                 N, NN);
}

// Round 18
// 216.813 us; speedup vs baseline: 1.0303x; 1.0031x over previous
//
#include <hip/hip_runtime.h>

#define DD 128   // feature dim
#define KY 512   // y columns (R * DD)
#define KT 640   // total GEMM K (KY + DD)
#define RR 4     // relations
#define BKT 16   // ints per (relation,node) bucket: [count, slot0..slot14]
#define CAPS 15  // usable slots per bucket
#define NKS (KT / 32)   // 20 K-steps

typedef short short8 __attribute__((ext_vector_type(8)));
typedef float f32x4 __attribute__((ext_vector_type(4)));
typedef float f32x2 __attribute__((ext_vector_type(2)));

union U4S8 { uint4 u; short8 s; };

__device__ __forceinline__ unsigned short f2bf(float f) {
  unsigned u = __float_as_uint(f);
  u += 0x7fffu + ((u >> 16) & 1u);   // round-to-nearest-even
  return (unsigned short)(u >> 16);
}

// ---- 1. fused prep: fill_slots FIRST, 4 edges/thread (MLP-4 = measured
//         optimum: MLP1 54.5 / MLP2 53 / MLP4 49.2 / MLP8 54); then xcast
//         (streams under the scatter), then wcast. r12/r14 verbatim. ----
// bucket layout node-major: slot[n*64 + r*16 + 0] = count, [+1..+15] = src ids.
// Count+slots share one 64B line -> ONE random line touch per edge (r4-verified).
__global__ __launch_bounds__(256) void prep(const float* __restrict__ x,
                                            const float* __restrict__ weight,
                                            const float* __restrict__ loopw,
                                            const int* __restrict__ src,
                                            const int* __restrict__ dst,
                                            unsigned short* __restrict__ xb,
                                            unsigned short* __restrict__ wt,
                                            int* __restrict__ slot,
                                            int N, int E, int FB, int XB) {
  int b = blockIdx.x;
  int t = threadIdx.x;
  if (b < FB) {
    // fill_slots: 4 edges per thread, int4-coalesced; independent atomics
    int i = (b * 256 + t) * 4;                  // RR*E divisible by 4
    if (i >= RR * E) return;
    int4 dp = *(const int4*)(dst + i);
    int4 sp = *(const int4*)(src + i);
    int r0 = i / E, r1 = (i + 1) / E, r2 = (i + 2) / E, r3 = (i + 3) / E;
    size_t b0 = ((size_t)dp.x * RR + r0) * BKT;
    size_t b1 = ((size_t)dp.y * RR + r1) * BKT;
    size_t b2 = ((size_t)dp.z * RR + r2) * BKT;
    size_t b3 = ((size_t)dp.w * RR + r3) * BKT;
    int p0 = atomicAdd(slot + b0, 1);
    int p1 = atomicAdd(slot + b1, 1);
    int p2 = atomicAdd(slot + b2, 1);
    int p3 = atomicAdd(slot + b3, 1);
    if (p0 < CAPS) slot[b0 + 1 + p0] = sp.x;
    if (p1 < CAPS) slot[b1 + 1 + p1] = sp.y;
    if (p2 < CAPS) slot[b2 + 1 + p2] = sp.z;
    if (p3 < CAPS) slot[b3 + 1 + p3] = sp.w;
  } else if (b < FB + XB) {
    // xcast: 8 floats per thread over N+1 rows (row N = zeros)
    int i = (b - FB) * 256 + t;
    if (i >= (N + 1) * 16) return;
    int n = i >> 4;
    uint4 o = make_uint4(0, 0, 0, 0);
    if (n < N) {
      const float4* xp = (const float4*)x + (size_t)i * 2;
      float4 v0 = xp[0], v1 = xp[1];
      o.x = (unsigned)f2bf(v0.x) | ((unsigned)f2bf(v0.y) << 16);
      o.y = (unsigned)f2bf(v0.z) | ((unsigned)f2bf(v0.w) << 16);
      o.z = (unsigned)f2bf(v1.x) | ((unsigned)f2bf(v1.y) << 16);
      o.w = (unsigned)f2bf(v1.z) | ((unsigned)f2bf(v1.w) << 16);
    }
    ((uint4*)xb)[i] = o;
  } else {
    // wcast into kstep-tile layout:
    // i = ks*4096 + c*512 + l*8 + j -> B[k = ks*32+(l>>4)*8+j][col = c*16+(l&15)]
    int i = (b - FB - XB) * 256 + t;
    if (i >= DD * KT) return;
    int j = i & 7, l = (i >> 3) & 63, c = (i >> 9) & 7, ks = i >> 12;
    int k = ks * 32 + (l >> 4) * 8 + j;
    int col = c * 16 + (l & 15);
    float v = (k < KY) ? weight[(size_t)((k >> 7) * DD + (k & (DD - 1))) * DD + col]
                       : loopw[(size_t)(k - KY) * DD + col];
    wt[i] = f2bf(v);
  }
}

// ---- 2. gather-aggregate (r11 loop body, kstep-major y write r17-verified).
//         NEW: accumulate into f32x2 so the two adds per packed uint fuse to
//         ONE v_pk_add_f32 (VOP3P) -> 3 VALU/uint instead of 4. Same op order,
//         bit-identical sums. r16 PMC: VALUBusy 61% = VALU slightly ahead of
//         BW; 25% VALU cut in the dominant loop. ----
__global__ __launch_bounds__(256) void gather_agg(const unsigned* __restrict__ xbu,
                                                  const int* __restrict__ slot,
                                                  unsigned* __restrict__ yu,
                                                  int NN /* = N+1 */) {
  int gid = blockIdx.x * 256 + threadIdx.x;
  int n = gid >> 6, lane = gid & 63;
  if (n >= NN) return;
  int N = NN - 1;  // zero-row index

  // all 4 buckets of this node in one coalesced 256B load (lane = r*16+j)
  int sv = slot[(size_t)n * 64 + lane];

  int cn[RR], ct[RR];
#pragma unroll
  for (int r = 0; r < RR; r++) {
    ct[r] = __builtin_amdgcn_readlane(sv, r << 4);    // count word (SGPR)
    cn[r] = ct[r] > CAPS ? CAPS : ct[r];
  }

  f32x2 aa[RR];
#pragma unroll
  for (int r = 0; r < RR; r++) aa[r] = (f32x2){0.f, 0.f};

#pragma unroll
  for (int rp = 0; rp < RR; rp += 2) {
    int mx = max(cn[rp], cn[rp + 1]);
    for (int u = 0; u < mx; u += 2) {                 // uniform trip count
      int i0 = (rp << 4) + 1 + u;
      int s0 = __builtin_amdgcn_readlane(sv, i0 & 63);
      int s1 = __builtin_amdgcn_readlane(sv, (i0 + 1) & 63);
      int s2 = __builtin_amdgcn_readlane(sv, (i0 + 16) & 63);
      int s3 = __builtin_amdgcn_readlane(sv, (i0 + 17) & 63);
      s0 = (u < cn[rp]) ? s0 : N;                     // pad -> zero row
      s1 = (u + 1 < cn[rp]) ? s1 : N;
      s2 = (u < cn[rp + 1]) ? s2 : N;
      s3 = (u + 1 < cn[rp + 1]) ? s3 : N;
      unsigned v0 = xbu[(size_t)s0 * 64 + lane];
      unsigned v1 = xbu[(size_t)s1 * 64 + lane];
      unsigned v2 = xbu[(size_t)s2 * 64 + lane];
      unsigned v3 = xbu[(size_t)s3 * 64 + lane];
      aa[rp] += (f32x2){__uint_as_float(v0 << 16),
                        __uint_as_float(v0 & 0xffff0000u)};
      aa[rp] += (f32x2){__uint_as_float(v1 << 16),
                        __uint_as_float(v1 & 0xffff0000u)};
      aa[rp + 1] += (f32x2){__uint_as_float(v2 << 16),
                            __uint_as_float(v2 & 0xffff0000u)};
      aa[rp + 1] += (f32x2){__uint_as_float(v3 << 16),
                            __uint_as_float(v3 & 0xffff0000u)};
    }
  }

  // kstep-major y write: kk = r*4 + (lane>>4), cu = lane&15
  int kk_lo = lane >> 4, cu = lane & 15;
#pragma unroll
  for (int r = 0; r < RR; r++) {
    float inv = 1.0f / (float)max(ct[r], 1);
    yu[((size_t)(r * 4 + kk_lo) * NN + n) * 16 + cu] =
        (unsigned)f2bf(aa[r][0] * inv) | ((unsigned)f2bf(aa[r][1] * inv) << 16);
  }
}

// ---- 3. MFMA GEMM: out = relu([y|xb][N,640] @ Wcat + bias) ----
// r17-verified: kstep-major y -> per-kstep A-load is one fully-contiguous
// 2KB block per wave. Structure = r11/r14 local optimum (probed+rejected:
// A-prefetch r12, BK=64 r15, 16-row waves r6, 512-thr r7). A: direct
// global->VGPR. B: double-buffered LDS, lane-linear kstep tiles
// (conflict-free ds_read_b128), 1-step reg prefetch.
__global__ __launch_bounds__(256) void gemm_mfma(const unsigned* __restrict__ yu,
                                                 const unsigned short* __restrict__ xb,
                                                 const uint4* __restrict__ wtv,
                                                 const float* __restrict__ bias,
                                                 float* __restrict__ out, int N, int NN) {
  __shared__ __align__(16) unsigned short Bs[2][4096];   // 16 KB total
  int t = threadIdx.x;
  int w = t >> 6, lane = t & 63;
  int m = lane & 15, q = lane >> 4;
  int rb = blockIdx.x * 128;

  int grow0 = rb + w * 32 + m, grow1 = grow0 + 16;
  int r0c = grow0 > N ? N : grow0;   // clamp to zero row N
  int r1c = grow1 > N ? N : grow1;
  const unsigned short* ax0 = xb + (size_t)r0c * DD + q * 8;
  const unsigned short* ax1 = xb + (size_t)r1c * DD + q * 8;

  // stage B kstep 0 (contiguous copy: 256 threads x 2 uint4)
  *(uint4*)(&Bs[0][t * 8]) = wtv[t];
  *(uint4*)(&Bs[0][2048 + t * 8]) = wtv[256 + t];
  __syncthreads();

  f32x4 acc[2][8];
#pragma unroll
  for (int i = 0; i < 2; i++)
#pragma unroll
    for (int c = 0; c < 8; c++) acc[i][c] = (f32x4){0.f, 0.f, 0.f, 0.f};

#pragma unroll
  for (int ks = 0; ks < NKS; ++ks) {
    const int buf = ks & 1;
    // issue-early: next B tile global->reg
    uint4 bs0, bs1;
    if (ks + 1 < NKS) {
      bs0 = wtv[(size_t)(ks + 1) * 512 + t];
      bs1 = wtv[(size_t)(ks + 1) * 512 + 256 + t];
    }

    // A fragments straight from global (compile-time y/xb branch)
    U4S8 a0, a1;
    if (ks < 16) {
      // kstep-major y: wave covers 32 consecutive nodes -> 2KB contiguous
      const unsigned* yb = yu + (size_t)ks * NN * 16 + q * 4;
      a0.u = *(const uint4*)(yb + (size_t)r0c * 16);
      a1.u = *(const uint4*)(yb + (size_t)r1c * 16);
    } else {
      a0.u = *(const uint4*)(ax0 + (ks - 16) * 32);
      a1.u = *(const uint4*)(ax1 + (ks - 16) * 32);
    }

    // B fragments: lane-linear -> conflict-free
    short8 bb[8];
#pragma unroll
    for (int c = 0; c < 8; ++c)
      bb[c] = *(const short8*)(&Bs[buf][(c * 64 + lane) * 8]);

#pragma unroll
    for (int c = 0; c < 8; ++c) {
      acc[0][c] = __builtin_amdgcn_mfma_f32_16x16x32_bf16(a0.s, bb[c], acc[0][c], 0, 0, 0);
      acc[1][c] = __builtin_amdgcn_mfma_f32_16x16x32_bf16(a1.s, bb[c], acc[1][c], 0, 0, 0);
    }

    // write-late: commit next B tile, then barrier
    if (ks + 1 < NKS) {
      *(uint4*)(&Bs[buf ^ 1][t * 8]) = bs0;
      *(uint4*)(&Bs[buf ^ 1][2048 + t * 8]) = bs1;
      __syncthreads();
    }
  }

  float bv[8];
#pragma unroll
  for (int c = 0; c < 8; ++c) bv[c] = bias[c * 16 + m];
#pragma unroll
  for (int i = 0; i < 2; ++i) {
    int rbase = rb + w * 32 + i * 16 + q * 4;
#pragma unroll
    for (int v = 0; v < 4; ++v) {
      int gr = rbase + v;
      if (gr < N) {
#pragma unroll
        for (int c = 0; c < 8; ++c)
          out[(size_t)gr * DD + c * 16 + m] = fmaxf(acc[i][c][v] + bv[c], 0.f);
      }
    }
  }
}

extern "C" void kernel_launch(void* const* d_in, const int* in_sizes, int n_in,
                              void* d_out, int out_size, void* d_ws, size_t ws_size,
                              hipStream_t stream) {
  const float* x      = (const float*)d_in[0];  // [N,128]
  const float* weight = (const float*)d_in[1];  // [R,128,128]
  const float* loop_w = (const float*)d_in[2];  // [128,128]
  const float* h_bias = (const float*)d_in[3];  // [128]
  const int*   src    = (const int*)d_in[4];    // [R,E]
  const int*   dst    = (const int*)d_in[5];    // [R,E]
  float* out = (float*)d_out;                   // [N,128]

  const int N = in_sizes[0] / DD;
  const int R = in_sizes[1] / (DD * DD);        // == RR == 4
  const int E = in_sizes[4] / R;
  const int RE = R * E;
  const int NN = N + 1;

  char* p = (char*)d_ws;
  auto alloc = [&](size_t bytes) {
    char* q = p;
    p += (bytes + 63) & ~size_t(63);
    return q;
  };
  int* slot = (int*)alloc((size_t)NN * RR * BKT * 4);           // [N+1][4][16] node-major
  unsigned short* wt = (unsigned short*)alloc((size_t)DD * KT * 2);
  unsigned short* xb = (unsigned short*)alloc((size_t)NN * DD * 2);  // +zero row
  unsigned short* y  = (unsigned short*)alloc((size_t)NN * KY * 2);  // kstep-major [16][NN][32]

  hipMemsetAsync(slot, 0, (size_t)NN * RR * BKT * 4, stream);

  int FB = (RE / 4 + 255) / 256;                // 4 edges/thread (MLP-4 optimum)
  int XB = (NN * 16 + 255) / 256;
  int WB = (DD * KT + 255) / 256;
  prep<<<FB + XB + WB, 256, 0, stream>>>(x, weight, loop_w, src, dst,
                                         xb, wt, slot, N, E, FB, XB);
  gather_agg<<<((size_t)NN * 64 + 255) / 256, 256, 0, stream>>>(
      (const unsigned*)xb, slot, (unsigned*)y, NN);
  gemm_mfma<<<(N + 127) / 128, 256, 0, stream>>>((const unsigned*)y, xb,
                                                 (const uint4*)wt, h_bias, out,
                                                 N, NN);
}